// Round 11
// baseline (149.700 us; speedup 1.0000x reference)
//
#include <hip/hip_runtime.h>
#include <hip/hip_bf16.h>

#define NROWS 8192
#define DDIM 64
#define BROWS 256          /* gram rows per block */
#define BCOLS 256          /* adj cols per block (64 per wave) */
#define CH 16              /* chunk rows */
#define NCH 16             /* chunks per block */

typedef __attribute__((ext_vector_type(8))) short short8v;
typedef __attribute__((ext_vector_type(4))) float f32x4;

#define K2CONST 2.885390081777927f  /* log2(e)/TAU, TAU=0.5 */
#define EPSC 1e-8f

#define AS1 __attribute__((address_space(1)))
#define AS3 __attribute__((address_space(3)))

// ---------------- Kernel 1: row L2-normalize (bf16 P + scaled Pk) ----------
__global__ __launch_bounds__(256) void k_normalize(
    const float* __restrict__ z, const float* __restrict__ za,
    __hip_bfloat16* __restrict__ Pb, __hip_bfloat16* __restrict__ Pk,
    float* __restrict__ dI1, float* __restrict__ dI2, float* __restrict__ dX) {
  int wid = (blockIdx.x * blockDim.x + threadIdx.x) >> 6;
  int lane = threadIdx.x & 63;
  if (wid >= NROWS) return;
  float x = z[wid * DDIM + lane];
  float y = za[wid * DDIM + lane];
  float sx = x * x, sy = y * y, sxy = x * y;
  for (int m = 1; m < 64; m <<= 1) {
    sx  += __shfl_xor(sx, m);
    sy  += __shfl_xor(sy, m);
    sxy += __shfl_xor(sxy, m);
  }
  float inx = 1.0f / fmaxf(sqrtf(sx), 1e-12f);
  float iny = 1.0f / fmaxf(sqrtf(sy), 1e-12f);
  float xn = x * inx, yn = y * iny;
  Pb[wid * DDIM + lane] = __float2bfloat16(xn);
  Pb[(NROWS + wid) * DDIM + lane] = __float2bfloat16(yn);
  Pk[wid * DDIM + lane] = __float2bfloat16(xn * K2CONST);
  Pk[(NROWS + wid) * DDIM + lane] = __float2bfloat16(yn * K2CONST);
  if (lane == 0) {
    dI1[wid] = expf(sx * inx * inx * 2.0f);   // /TAU = *2
    dI2[wid] = expf(sy * iny * iny * 2.0f);
    dX[wid]  = expf(sxy * iny * inx * 2.0f);
  }
}

// ---------------- Kernel 2: fused gram row-sums + adj-masked sums ----------
// Barrier-free wave-private pipelines. Block: 256 gram rows x 256 adj cols;
// wave w owns cols w*64..w*64+63 for ALL rows. Per 16-row chunk each wave
// stages its own 4KB adj slice + 2KB Pk copy (6 x global_load_lds) into a
// private 3-slot LDS ring; per-wave counted vmcnt, NO s_barrier in the loop.
// LDS layout is transposed at stage time (per-lane global source computes
// (row,colquad); dest linear in lane) -> all LDS reads are lane-consecutive
// 16B slots: conflict-free by construction.
// Compute (validated R6/R8/R9): g = mfma(colfrag, rowfrag); lane (r_in,kq)
// reg c holds gram(row = r_in, col = t*16 + kq*4 + c).
__global__ __launch_bounds__(256) void k_fused(
    const __hip_bfloat16* __restrict__ Pb, const __hip_bfloat16* __restrict__ Pk,
    const float* __restrict__ adj, const float* __restrict__ adj_aug,
    float* __restrict__ sD, float* __restrict__ sM, float* __restrict__ cnt) {
  __shared__ __align__(16) char lds[4][3][6144];   // wave x slot x (4KB adj + 2KB pk)

  const int tid = threadIdx.x;
  const int w = tid >> 6, lane = tid & 63;
  const int r_in = lane & 15, kq = lane >> 4;
  const int rb = blockIdx.x >> 5;          // 0..63 row-groups of 256 gram rows
  const int cb = blockIdx.x & 31;          // 0..31 col-groups of 256 cols
  const int grow0 = rb * BROWS;
  const int c0 = cb * BCOLS + w * 64;      // this wave's 64-col slice
  const float* ADJ = (rb < 32) ? adj : adj_aug;
  const int arow0 = (rb & 31) * BROWS;

  // ---- col fragments (A operand) for this wave's 64 cols, fixed ----
  const short8v* P8 = reinterpret_cast<const short8v*>(Pb);
  short8v bA0[4], bA1[4], bB0[4], bB1[4];
#pragma unroll
  for (int t = 0; t < 4; t++) {
    int col = c0 + t * 16 + r_in;
    bA0[t] = P8[col * 8 + kq];
    bA1[t] = P8[col * 8 + kq + 4];
    bB0[t] = P8[(col + NROWS) * 8 + kq];
    bB1[t] = P8[(col + NROWS) * 8 + kq + 4];
  }
  asm volatile("s_waitcnt vmcnt(0)" ::: "memory");  // clean vm queue for counting

  // per-lane global sources; staging lane decomposition: row=lane&15, quad=lane>>4
  const float* asrc = ADJ + (size_t)(arow0 + r_in) * NROWS + c0 + kq * 4;
  const __hip_bfloat16* psrc = Pk + (size_t)(grow0 + r_in) * DDIM + kq * 8;

  // adj load u fills colquads u*4..u*4+3 x 16 rows (dest lane-linear);
  // pk load h fills half h (dims h*32..h*32+31) x 16 rows.
#define STAGE(K) {                                                             \
    char* db_ = &lds[w][(K) % 3][0];                                           \
    _Pragma("unroll")                                                          \
    for (int u = 0; u < 4; u++)                                                \
      __builtin_amdgcn_global_load_lds(                                        \
          (const AS1 unsigned int*)(asrc + (size_t)(K) * (CH * NROWS) + u*16), \
          (AS3 unsigned int*)(db_ + u * 1024), 16, 0, 0);                      \
    _Pragma("unroll")                                                          \
    for (int h = 0; h < 2; h++)                                                \
      __builtin_amdgcn_global_load_lds(                                        \
          (const AS1 unsigned int*)(psrc + (size_t)(K) * (CH * DDIM) + h*32),  \
          (AS3 unsigned int*)(db_ + 4096 + h * 1024), 16, 0, 0);               \
  }

#define CHUNK(K, WAITSTR, DOSTAGE) {                                           \
    asm volatile(WAITSTR ::: "memory");                                        \
    const char* sb_ = &lds[w][(K) % 3][0];                                     \
    short8v a0 = *(const short8v*)(sb_ + 4096 + (kq * 16 + r_in) * 16);        \
    short8v a1 = *(const short8v*)(sb_ + 5120 + (kq * 16 + r_in) * 16);        \
    float dsum = 0.f, msum = 0.f, csum = 0.f;                                  \
    _Pragma("unroll")                                                          \
    for (int t = 0; t < 4; t++) {                                              \
      f32x4 av = *(const f32x4*)(sb_ + t * 1024 + kq * 256 + r_in * 16);       \
      f32x4 g0 = (f32x4){0.f, 0.f, 0.f, 0.f};                                  \
      g0 = __builtin_amdgcn_mfma_f32_16x16x32_bf16(bA0[t], a0, g0, 0, 0, 0);   \
      g0 = __builtin_amdgcn_mfma_f32_16x16x32_bf16(bA1[t], a1, g0, 0, 0, 0);   \
      f32x4 g1 = (f32x4){0.f, 0.f, 0.f, 0.f};                                  \
      g1 = __builtin_amdgcn_mfma_f32_16x16x32_bf16(bB0[t], a0, g1, 0, 0, 0);   \
      g1 = __builtin_amdgcn_mfma_f32_16x16x32_bf16(bB1[t], a1, g1, 0, 0, 0);   \
      _Pragma("unroll")                                                        \
      for (int c = 0; c < 4; c++) {                                            \
        float e = __builtin_amdgcn_exp2f(g0[c]) + __builtin_amdgcn_exp2f(g1[c]);\
        dsum += e; msum += av[c] * e; csum += av[c];                           \
      }                                                                        \
    }                                                                          \
    dsum += __shfl_xor(dsum, 16); dsum += __shfl_xor(dsum, 32);                \
    msum += __shfl_xor(msum, 16); msum += __shfl_xor(msum, 32);                \
    csum += __shfl_xor(csum, 16); csum += __shfl_xor(csum, 32);                \
    if (lane < 16) {                                                           \
      int row_ = grow0 + (K) * CH + r_in;                                      \
      atomicAdd(&sD[row_], dsum);                                              \
      atomicAdd(&sM[row_], msum);                                              \
      atomicAdd(&cnt[row_], csum);                                             \
    }                                                                          \
    if (DOSTAGE) STAGE((K) + 3);                                               \
  }

  // prologue: 3 chunks in flight (18 loads)
  STAGE(0); STAGE(1); STAGE(2);

  // vmcnt ledger (6 loads/stage, 3 atomics/chunk, in-order retire):
  // k=0: [s1,s2]+drain s0 -> 12 ; k=1: [s2,a0,s3] -> 15 ;
  // k=2..13: [a(k-2),s(k+1),a(k-1),s(k+2)] -> 18 ;
  // k=14: [a12,s15,a13] -> 12 ; k=15: [a13,a14] -> 6.
  CHUNK(0, "s_waitcnt vmcnt(12)", true);
  CHUNK(1, "s_waitcnt vmcnt(15)", true);
  for (int k = 2; k <= 12; k++) {
    CHUNK(k, "s_waitcnt vmcnt(18)", true);
  }
  CHUNK(13, "s_waitcnt vmcnt(18)", false);
  CHUNK(14, "s_waitcnt vmcnt(12)", false);
  CHUNK(15, "s_waitcnt vmcnt(6)",  false);
#undef CHUNK
#undef STAGE
}

// ---------------- Final: per-row loss, partial sums ----------------
__global__ __launch_bounds__(256) void k_final_partial(
    const float* __restrict__ sD, const float* __restrict__ sM,
    const float* __restrict__ dI1, const float* __restrict__ dI2,
    const float* __restrict__ dX,
    const float* __restrict__ cnt, float* __restrict__ acc) {
  int i = blockIdx.x * blockDim.x + threadIdx.x;  // 32 blocks x 256 = 8192
  float pos1 = dX[i] + sM[i];
  float den1 = sD[i] - dI1[i];
  float l1 = logf(pos1 / (den1 + EPSC) + EPSC) / (2.0f * cnt[i] + 1.0f);
  float pos2 = dX[i] + sM[NROWS + i];
  float den2 = sD[NROWS + i] - dI2[i];
  float l2 = logf(pos2 / (den2 + EPSC) + EPSC) / (2.0f * cnt[NROWS + i] + 1.0f);
  float local = l1 + l2;
#pragma unroll
  for (int m = 1; m < 64; m <<= 1) local += __shfl_xor(local, m);
  if ((threadIdx.x & 63) == 0) atomicAdd(acc, local);
}

__global__ void k_finalize(const float* __restrict__ acc, float* __restrict__ out) {
  out[0] = -acc[0] * (0.5f / (float)NROWS);
}

extern "C" void kernel_launch(void* const* d_in, const int* in_sizes, int n_in,
                              void* d_out, int out_size, void* d_ws, size_t ws_size,
                              hipStream_t stream) {
  const float* z       = (const float*)d_in[0];
  const float* za      = (const float*)d_in[1];
  const float* adj     = (const float*)d_in[2];
  const float* adj_aug = (const float*)d_in[3];

  float* ws = (float*)d_ws;
  __hip_bfloat16* Pb = (__hip_bfloat16*)ws;              // 16384*64 bf16
  __hip_bfloat16* Pk = (__hip_bfloat16*)(ws + 524288);   // scaled copy
  float* Z0   = ws + 1048576;   // zeroed region: 3*16384 + 1 floats
  float* sD   = Z0;             // 16384
  float* sM   = Z0 + 16384;     // 16384
  float* cnt  = Z0 + 32768;     // 16384
  float* acc  = Z0 + 49152;     // 1
  float* dI1  = Z0 + 49153;     // 8192
  float* dI2  = dI1 + 8192;     // 8192
  float* dX   = dI2 + 8192;     // 8192

  hipMemsetAsync(Z0, 0, 49153 * sizeof(float), stream);

  k_normalize<<<2048, 256, 0, stream>>>(z, za, Pb, Pk, dI1, dI2, dX);
  k_fused<<<2048, 256, 0, stream>>>(Pb, Pk, adj, adj_aug, sD, sM, cnt);
  k_final_partial<<<32, 256, 0, stream>>>(sD, sM, dI1, dI2, dX, cnt, acc);
  k_finalize<<<1, 1, 0, stream>>>(acc, (float*)d_out);
}